// Round 4
// baseline (27479.315 us; speedup 1.0000x reference)
//
#include <hip/hip_runtime.h>
#include <hip/hip_bf16.h>

#define BB 64
#define SS 196
#define EE 512
#define DD 2048
#define MM 25
#define HNN 32
#define NHH 8
#define TT 50
#define NSS 512
#define OUTN 1000
#define HDD 64
#define KSYN 2560
#define NSYN 4096

#define CERT_OFF 3200000
#define SYNC_OFF 3206400

// ---------------- f32 GEMM: C(M,N) = A(M,K) @ W(K,N) + bias ----------------
// LAYOUT 0: row-major f32 out. LAYOUT 1: attention permute ((b*NH+h)*S+s)*HD+d
template<int LAYOUT>
__global__ __launch_bounds__(256) void sgemm(
    const float* __restrict__ Ag, const float* __restrict__ Wg,
    const float* __restrict__ bias, float* __restrict__ Cg,
    int Mg, int Ng, int Kg)
{
  __shared__ float As[16][68];   // [k][m]
  __shared__ float Bs[16][68];   // [k][n]
  int t = threadIdx.x;
  int bm = blockIdx.x * 64, bn = blockIdx.y * 64;
  int ty = t >> 4, tx = t & 15;
  int atm = t >> 2, atk = (t & 3) * 4;
  int bkk = t >> 4, bnn = (t & 15) * 4;
  float c[4][4] = {};
  for (int k0 = 0; k0 < Kg; k0 += 16){
    float4 av = *reinterpret_cast<const float4*>(Ag + (size_t)(bm + atm) * Kg + k0 + atk);
    As[atk][atm] = av.x; As[atk + 1][atm] = av.y;
    As[atk + 2][atm] = av.z; As[atk + 3][atm] = av.w;
    float4 bv = *reinterpret_cast<const float4*>(Wg + (size_t)(k0 + bkk) * Ng + bn + bnn);
    *reinterpret_cast<float4*>(&Bs[bkk][bnn]) = bv;
    __syncthreads();
    #pragma unroll
    for (int k = 0; k < 16; k++){
      float4 a = *reinterpret_cast<const float4*>(&As[k][ty * 4]);
      float4 b = *reinterpret_cast<const float4*>(&Bs[k][tx * 4]);
      c[0][0] += a.x * b.x; c[0][1] += a.x * b.y; c[0][2] += a.x * b.z; c[0][3] += a.x * b.w;
      c[1][0] += a.y * b.x; c[1][1] += a.y * b.y; c[1][2] += a.y * b.z; c[1][3] += a.y * b.w;
      c[2][0] += a.z * b.x; c[2][1] += a.z * b.y; c[2][2] += a.z * b.z; c[2][3] += a.z * b.w;
      c[3][0] += a.w * b.x; c[3][1] += a.w * b.y; c[3][2] += a.w * b.z; c[3][3] += a.w * b.w;
    }
    __syncthreads();
  }
  #pragma unroll
  for (int j = 0; j < 4; j++){
    int col = bn + tx * 4 + j;
    float bvv = bias[col];
    #pragma unroll
    for (int i = 0; i < 4; i++){
      int row = bm + ty * 4 + i;
      float v = c[i][j] + bvv;
      if (LAYOUT == 0){
        Cg[(size_t)row * Ng + col] = v;
      } else {
        int b = row / SS, s = row - b * SS;
        int h = col >> 6, d = col & 63;
        Cg[(((size_t)b * NHH + h) * SS + s) * HDD + d] = v;
      }
    }
  }
}

// ---------------- LayerNorm rows of (12544, 512), f32 -> f32 ----------------
__global__ __launch_bounds__(256) void ln_rows_kernel(const float* __restrict__ y,
    const float* __restrict__ g, const float* __restrict__ bb,
    float* __restrict__ outf)
{
  int r = blockIdx.x, t = threadIdx.x;
  __shared__ float red[256];
  const float* row = y + (size_t)r * EE;
  float v0 = row[t], v1 = row[t + 256];
  red[t] = v0 + v1; __syncthreads();
  for (int st = 128; st > 0; st >>= 1){ if (t < st) red[t] += red[t + st]; __syncthreads(); }
  float mean = red[0] * (1.f / EE); __syncthreads();
  float d0 = v0 - mean, d1 = v1 - mean;
  red[t] = d0 * d0 + d1 * d1; __syncthreads();
  for (int st = 128; st > 0; st >>= 1){ if (t < st) red[t] += red[t + st]; __syncthreads(); }
  float rs = 1.f / sqrtf(red[0] * (1.f / EE) + 1e-5f);
  float* orow = outf + (size_t)r * EE;
  orow[t] = d0 * rs * g[t] + bb[t];
  orow[t + 256] = d1 * rs * g[t + 256] + bb[t + 256];
}

// ---------------- init recurrent state ----------------
__global__ __launch_bounds__(256) void init_kernel(const float* __restrict__ sa,
    const float* __restrict__ strace,
    const int* __restrict__ ol, const int* __restrict__ orr,
    float* __restrict__ act, float* __restrict__ tr,
    float* __restrict__ aA, float* __restrict__ bA,
    float* __restrict__ aO, float* __restrict__ bO)
{
  int tid = blockIdx.x * 256 + threadIdx.x;
  int b = tid >> 11, d = tid & 2047;
  act[tid] = sa[d];
  for (int m = 0; m < MM; m++)
    tr[((size_t)b * MM + m) * DD + d] = strace[d * MM + m];
  if (tid < BB * NSS){
    int n = tid & (NSS - 1);
    aO[tid] = sa[ol[n]] * sa[orr[n]];
    bO[tid] = 1.f; aA[tid] = 0.f; bA[tid] = 0.f;
  }
}

// ---------------- step: action-sync update + q + qh ----------------
__global__ __launch_bounds__(512) void k_sync_qq(const float* __restrict__ act,
    float* __restrict__ aA, float* __restrict__ bA,
    const float* __restrict__ decayA,
    const int* __restrict__ il, const int* __restrict__ ir,
    const float* __restrict__ Wq, const float* __restrict__ bq,
    const float* __restrict__ Wqa, const float* __restrict__ bqa,
    float* __restrict__ qh)
{
  int b = blockIdx.x, n = threadIdx.x;
  __shared__ float sA[NSS];
  __shared__ float qv[EE];
  float p = act[b * DD + il[n]] * act[b * DD + ir[n]];
  float r = expf(-fminf(fmaxf(decayA[n], 0.f), 15.f));
  float na = r * aA[b * NSS + n] + p;
  float nb = r * bA[b * NSS + n] + 1.f;
  aA[b * NSS + n] = na; bA[b * NSS + n] = nb;
  sA[n] = na / sqrtf(nb);
  __syncthreads();
  float acc = bq[n];
  #pragma unroll 4
  for (int k = 0; k < NSS; k++) acc += sA[k] * Wq[k * EE + n];
  qv[n] = acc;
  __syncthreads();
  float acc2 = bqa[n];
  #pragma unroll 4
  for (int k = 0; k < EE; k++) acc2 += qv[k] * Wqa[k * EE + n];
  qh[b * EE + n] = acc2;
}

// ---------------- step: attention (one block per (b,h)) ----------------
__global__ __launch_bounds__(256) void k_attn(const float* __restrict__ qh,
    const float* __restrict__ kh, const float* __restrict__ vh,
    float* __restrict__ attnout)
{
  int bh = blockIdx.x, tid = threadIdx.x;
  int b = bh >> 3, h = bh & 7;
  __shared__ float qs[HDD];
  __shared__ float ps[SS];
  __shared__ float red[256];
  const float* khp = kh + (size_t)bh * SS * HDD;
  const float* vhp = vh + (size_t)bh * SS * HDD;
  if (tid < HDD) qs[tid] = qh[b * EE + h * HDD + tid];
  __syncthreads();
  float sc = -1e30f;
  if (tid < SS){
    const float* kr = khp + (size_t)tid * HDD;
    float acc = 0.f;
    #pragma unroll
    for (int d2 = 0; d2 < HDD; d2 += 4){
      float4 kv = *reinterpret_cast<const float4*>(kr + d2);
      acc += qs[d2] * kv.x + qs[d2 + 1] * kv.y + qs[d2 + 2] * kv.z + qs[d2 + 3] * kv.w;
    }
    sc = acc * 0.125f;
  }
  red[tid] = sc; __syncthreads();
  for (int st = 128; st > 0; st >>= 1){ if (tid < st) red[tid] = fmaxf(red[tid], red[tid + st]); __syncthreads(); }
  float mx = red[0]; __syncthreads();
  float pv = 0.f;
  if (tid < SS){ pv = expf(sc - mx); ps[tid] = pv; }
  red[tid] = pv; __syncthreads();
  for (int st = 128; st > 0; st >>= 1){ if (tid < st) red[tid] += red[tid + st]; __syncthreads(); }
  float inv = 1.f / red[0]; __syncthreads();
  int d = tid & 63, cs = tid >> 6;
  float acc2 = 0.f;
  for (int s2 = cs; s2 < SS; s2 += 4)
    acc2 += ps[s2] * vhp[(size_t)s2 * HDD + d];
  red[tid] = acc2; __syncthreads();
  if (tid < 64){
    float v = red[tid] + red[tid + 64] + red[tid + 128] + red[tid + 192];
    attnout[b * EE + h * HDD + tid] = v * inv;
  }
}

// ---------------- step: attn @ Wo + bo ----------------
__global__ __launch_bounds__(512) void k_wo(const float* __restrict__ attnout,
    const float* __restrict__ Wo, const float* __restrict__ bo,
    float* __restrict__ attnproj)
{
  int b = blockIdx.x, n = threadIdx.x;
  __shared__ float arow[EE];
  arow[n] = attnout[b * EE + n];
  __syncthreads();
  float acc = bo[n];
  #pragma unroll 4
  for (int k = 0; k < EE; k++) acc += arow[k] * Wo[k * EE + n];
  attnproj[b * EE + n] = acc;
}

// ---------------- step: synapse GEMM: concat(attnproj, act)(64x2560) @ Wsyn(2560x4096) ----------------
__global__ __launch_bounds__(256) void k_syn(const float* __restrict__ attnproj,
    const float* __restrict__ act, const float* __restrict__ Wsyn,
    const float* __restrict__ bsyn, float* __restrict__ glupre)
{
  __shared__ float Ak[64][68];   // [k][m]
  __shared__ float Bf[64][36];   // [k][n]
  int t = threadIdx.x;
  int bn = blockIdx.x * 32;
  int ty = t >> 4, tx = t & 15;
  int atm = t >> 2;              // row 0..63
  int atk = (t & 3) * 16;        // k base
  int bkk = t >> 3;              // 0..31
  int bnn = (t & 7) * 4;
  float c[4][2] = {};
  for (int k0 = 0; k0 < KSYN; k0 += 64){
    #pragma unroll
    for (int jj = 0; jj < 4; jj++){
      int gk = k0 + atk + jj * 4;
      float4 av = (gk < EE)
        ? *reinterpret_cast<const float4*>(attnproj + (size_t)atm * EE + gk)
        : *reinterpret_cast<const float4*>(act + (size_t)atm * DD + (gk - EE));
      Ak[atk + jj * 4 + 0][atm] = av.x;
      Ak[atk + jj * 4 + 1][atm] = av.y;
      Ak[atk + jj * 4 + 2][atm] = av.z;
      Ak[atk + jj * 4 + 3][atm] = av.w;
    }
    float4 b0 = *reinterpret_cast<const float4*>(Wsyn + (size_t)(k0 + bkk) * NSYN + bn + bnn);
    float4 b1 = *reinterpret_cast<const float4*>(Wsyn + (size_t)(k0 + bkk + 32) * NSYN + bn + bnn);
    *reinterpret_cast<float4*>(&Bf[bkk][bnn]) = b0;
    *reinterpret_cast<float4*>(&Bf[bkk + 32][bnn]) = b1;
    __syncthreads();
    #pragma unroll
    for (int k = 0; k < 64; k++){
      float4 a = *reinterpret_cast<const float4*>(&Ak[k][ty * 4]);
      float2 b = *reinterpret_cast<const float2*>(&Bf[k][tx * 2]);
      c[0][0] += a.x * b.x; c[0][1] += a.x * b.y;
      c[1][0] += a.y * b.x; c[1][1] += a.y * b.y;
      c[2][0] += a.z * b.x; c[2][1] += a.z * b.y;
      c[3][0] += a.w * b.x; c[3][1] += a.w * b.y;
    }
    __syncthreads();
  }
  int col = bn + tx * 2;
  float bs0 = bsyn[col], bs1 = bsyn[col + 1];
  #pragma unroll
  for (int i = 0; i < 4; i++){
    int row = ty * 4 + i;
    glupre[(size_t)row * NSYN + col]     = c[i][0] + bs0;
    glupre[(size_t)row * NSYN + col + 1] = c[i][1] + bs1;
  }
}

// ---------------- step: GLU + LayerNorm (two-pass var) -> write trace slot ----------------
__global__ __launch_bounds__(256) void k_gluln(const float* __restrict__ glupre,
    const float* __restrict__ g, const float* __restrict__ bb,
    float* __restrict__ tr, int slot)
{
  int b = blockIdx.x, t = threadIdx.x;
  __shared__ float u[DD];
  __shared__ float red[256];
  float ls = 0.f;
  for (int i = t; i < DD; i += 256){
    float x0 = glupre[(size_t)b * NSYN + i];
    float x1 = glupre[(size_t)b * NSYN + DD + i];
    float uu = x0 / (1.f + expf(-x1));
    u[i] = uu; ls += uu;
  }
  red[t] = ls; __syncthreads();
  for (int st = 128; st > 0; st >>= 1){ if (t < st) red[t] += red[t + st]; __syncthreads(); }
  float mean = red[0] * (1.f / DD); __syncthreads();
  float lq = 0.f;
  for (int i = t; i < DD; i += 256){
    float dv = u[i] - mean; lq += dv * dv;
  }
  red[t] = lq; __syncthreads();
  for (int st = 128; st > 0; st >>= 1){ if (t < st) red[t] += red[t + st]; __syncthreads(); }
  float rs = 1.f / sqrtf(red[0] * (1.f / DD) + 1e-5f);
  float* out = tr + ((size_t)b * MM + slot) * DD;
  for (int i = t; i < DD; i += 256)
    out[i] = (u[i] - mean) * rs * g[i] + bb[i];
}

// ---------------- step: per-neuron deep MLP over trace history ----------------
__global__ __launch_bounds__(256) void k_nlm(const float* __restrict__ tr,
    const float* __restrict__ w1, const float* __restrict__ b1,
    const float* __restrict__ w2, const float* __restrict__ b2,
    float* __restrict__ act, int ts)
{
  int tid = blockIdx.x * 256 + threadIdx.x;
  int b = tid >> 11, d = tid & 2047;
  float hp[64];
  #pragma unroll
  for (int h2 = 0; h2 < 64; h2++) hp[h2] = b1[d * 64 + h2];
  for (int j = 0; j < MM; j++){
    int slot = (ts + 1 + j) % MM;
    float tv = tr[((size_t)b * MM + slot) * DD + d];
    const float* w1p = w1 + ((size_t)j * 64) * DD + d;
    #pragma unroll
    for (int h2 = 0; h2 < 64; h2++) hp[h2] += tv * w1p[(size_t)h2 * DD];
  }
  float o0 = b2[d * 2], o1 = b2[d * 2 + 1];
  #pragma unroll
  for (int h2 = 0; h2 < HNN; h2++){
    float hh = hp[h2] / (1.f + expf(-hp[h2 + HNN]));
    o0 += hh * w2[((size_t)(h2 * 2)) * DD + d];
    o1 += hh * w2[((size_t)(h2 * 2 + 1)) * DD + d];
  }
  act[tid] = o0 / (1.f + expf(-o1));
}

// ---------------- step: out-sync update + prediction + certainty (f32 outputs) ----------------
__global__ __launch_bounds__(512) void k_out(const float* __restrict__ act,
    float* __restrict__ aO, float* __restrict__ bO,
    const float* __restrict__ decayO,
    const int* __restrict__ ol, const int* __restrict__ orr,
    const float* __restrict__ Wout, const float* __restrict__ bout,
    float* __restrict__ dout, int ts)
{
  int b = blockIdx.x, n = threadIdx.x;
  __shared__ float so[NSS];
  __shared__ float pl[OUTN];
  __shared__ float red[512];
  float p = act[b * DD + ol[n]] * act[b * DD + orr[n]];
  float r = expf(-fminf(fmaxf(decayO[n], 0.f), 15.f));
  float na = r * aO[b * NSS + n] + p;
  float nb = r * bO[b * NSS + n] + 1.f;
  aO[b * NSS + n] = na; bO[b * NSS + n] = nb;
  float sv = na / sqrtf(nb);
  so[n] = sv;
  if (ts == TT - 1) dout[SYNC_OFF + b * NSS + n] = sv;
  __syncthreads();
  for (int nn = n; nn < OUTN; nn += NSS){
    float acc = bout[nn];
    #pragma unroll 4
    for (int k = 0; k < NSS; k++) acc += so[k] * Wout[k * OUTN + nn];
    pl[nn] = acc;
    dout[((size_t)b * OUTN + nn) * TT + ts] = acc;
  }
  __syncthreads();
  float mx = -1e30f;
  for (int nn = n; nn < OUTN; nn += NSS) mx = fmaxf(mx, pl[nn]);
  red[n] = mx; __syncthreads();
  for (int st = 256; st > 0; st >>= 1){ if (n < st) red[n] = fmaxf(red[n], red[n + st]); __syncthreads(); }
  mx = red[0]; __syncthreads();
  float z = 0.f, s1 = 0.f;
  for (int nn = n; nn < OUTN; nn += NSS){
    float e = expf(pl[nn] - mx);
    z += e; s1 += e * (pl[nn] - mx);
  }
  red[n] = z; __syncthreads();
  for (int st = 256; st > 0; st >>= 1){ if (n < st) red[n] += red[n + st]; __syncthreads(); }
  z = red[0]; __syncthreads();
  red[n] = s1; __syncthreads();
  for (int st = 256; st > 0; st >>= 1){ if (n < st) red[n] += red[n + st]; __syncthreads(); }
  s1 = red[0];
  if (n == 0){
    float logZ = logf(z);
    float ne = (logZ - s1 / z) * (1.f / logf(1000.f));
    dout[CERT_OFF + (b * 2 + 0) * TT + ts] = ne;
    dout[CERT_OFF + (b * 2 + 1) * TT + ts] = 1.f - ne;
  }
}

extern "C" void kernel_launch(void* const* d_in, const int* in_sizes, int n_in,
                              void* d_out, int out_size, void* d_ws, size_t ws_size,
                              hipStream_t stream)
{
  const float* x    = (const float*)d_in[0];
  const float* Wkv  = (const float*)d_in[1];
  const float* bkv  = (const float*)d_in[2];
  const float* gkv  = (const float*)d_in[3];
  const float* bkv2 = (const float*)d_in[4];
  const float* Wq   = (const float*)d_in[5];
  const float* bq   = (const float*)d_in[6];
  const float* Wqa  = (const float*)d_in[7];
  const float* bqa  = (const float*)d_in[8];
  const float* Wka  = (const float*)d_in[9];
  const float* bka  = (const float*)d_in[10];
  const float* Wva  = (const float*)d_in[11];
  const float* bva  = (const float*)d_in[12];
  const float* Wo   = (const float*)d_in[13];
  const float* bo   = (const float*)d_in[14];
  const float* Wsyn = (const float*)d_in[15];
  const float* bsyn = (const float*)d_in[16];
  const float* gsyn = (const float*)d_in[17];
  const float* bsn  = (const float*)d_in[18];
  const float* w1   = (const float*)d_in[19];
  const float* b1   = (const float*)d_in[20];
  const float* w2   = (const float*)d_in[21];
  const float* b2   = (const float*)d_in[22];
  const float* sact = (const float*)d_in[23];
  const float* strc = (const float*)d_in[24];
  const float* dcA  = (const float*)d_in[25];
  const float* dcO  = (const float*)d_in[26];
  const float* Wout = (const float*)d_in[27];
  const float* bout = (const float*)d_in[28];
  const int* ial = (const int*)d_in[29];
  const int* iar = (const int*)d_in[30];
  const int* iol = (const int*)d_in[31];
  const int* ior = (const int*)d_in[32];

  char* ws = (char*)d_ws;
  float* kh = (float*)ws;                         // 25,690,112 B
  float* vh = (float*)(ws + 25690112);            // 25,690,112 B
  char* scr = ws + 51380224;
  float* kvnf  = (float*)ws;                      // pre-LN (aliases kh; dead before kh written)
  float* kvnln = (float*)scr;                     // post-LN (dead before state init)
  float* tr       = (float*)scr;                  // 13,107,200 B (B,M,D)
  float* act      = (float*)(scr + 13107200);
  float* aA       = (float*)(scr + 13631488);
  float* bA       = (float*)(scr + 13762560);
  float* aO       = (float*)(scr + 13893632);
  float* bO       = (float*)(scr + 14024704);
  float* qh       = (float*)(scr + 14155776);
  float* attnout  = (float*)(scr + 14286848);
  float* attnproj = (float*)(scr + 14417920);
  float* glupre   = (float*)(scr + 14548992);     // 1,048,576 B
  float* dout = (float*)d_out;

  // precompute: kv = LN(x@Wkv+bkv); kh = kv@Wka+bka; vh = kv@Wva+bva
  sgemm<0><<<dim3(196, 8), 256, 0, stream>>>(x, Wkv, bkv, kvnf, 12544, EE, EE);
  ln_rows_kernel<<<12544, 256, 0, stream>>>(kvnf, gkv, bkv2, kvnln);
  sgemm<1><<<dim3(196, 8), 256, 0, stream>>>(kvnln, Wka, bka, kh, 12544, EE, EE);
  sgemm<1><<<dim3(196, 8), 256, 0, stream>>>(kvnln, Wva, bva, vh, 12544, EE, EE);
  init_kernel<<<512, 256, 0, stream>>>(sact, strc, iol, ior, act, tr, aA, bA, aO, bO);

  for (int t = 0; t < TT; t++){
    k_sync_qq<<<64, 512, 0, stream>>>(act, aA, bA, dcA, ial, iar, Wq, bq, Wqa, bqa, qh);
    k_attn<<<512, 256, 0, stream>>>(qh, kh, vh, attnout);
    k_wo<<<64, 512, 0, stream>>>(attnout, Wo, bo, attnproj);
    k_syn<<<128, 256, 0, stream>>>(attnproj, act, Wsyn, bsyn, glupre);
    k_gluln<<<64, 256, 0, stream>>>(glupre, gsyn, bsn, tr, t % MM);
    k_nlm<<<512, 256, 0, stream>>>(tr, w1, b1, w2, b2, act, t);
    k_out<<<64, 512, 0, stream>>>(act, aO, bO, dcO, iol, ior, Wout, bout, dout, t);
  }
}

// Round 5
// 8434.454 us; speedup vs baseline: 3.2580x; 3.2580x over previous
//
#include <hip/hip_runtime.h>

#define BB 64
#define SS 196
#define EE 512
#define DD 2048
#define MM 25
#define HNN 32
#define NHH 8
#define TT 50
#define NSS 512
#define OUTN 1000
#define HDD 64
#define KSYN 2560
#define NSYN 4096
#define KQ 8
#define KQLEN 320

#define CERT_OFF 3200000
#define SYNC_OFF 3206400

__device__ __forceinline__ float sigm(float x){ return 1.f / (1.f + expf(-x)); }

// ---------------- f32 GEMM (precompute): C(M,N) = A(M,K) @ W(K,N) + bias ----------------
// LAYOUT 0: row-major f32 out. LAYOUT 1: attention permute ((b*NH+h)*S+s)*HD+d
template<int LAYOUT>
__global__ __launch_bounds__(256) void sgemm(
    const float* __restrict__ Ag, const float* __restrict__ Wg,
    const float* __restrict__ bias, float* __restrict__ Cg,
    int Mg, int Ng, int Kg)
{
  __shared__ float As[16][68];   // [k][m]
  __shared__ float Bs[16][68];   // [k][n]
  int t = threadIdx.x;
  int bm = blockIdx.x * 64, bn = blockIdx.y * 64;
  int ty = t >> 4, tx = t & 15;
  int atm = t >> 2, atk = (t & 3) * 4;
  int bkk = t >> 4, bnn = (t & 15) * 4;
  float c[4][4] = {};
  for (int k0 = 0; k0 < Kg; k0 += 16){
    float4 av = *reinterpret_cast<const float4*>(Ag + (size_t)(bm + atm) * Kg + k0 + atk);
    As[atk][atm] = av.x; As[atk + 1][atm] = av.y;
    As[atk + 2][atm] = av.z; As[atk + 3][atm] = av.w;
    float4 bv = *reinterpret_cast<const float4*>(Wg + (size_t)(k0 + bkk) * Ng + bn + bnn);
    *reinterpret_cast<float4*>(&Bs[bkk][bnn]) = bv;
    __syncthreads();
    #pragma unroll
    for (int k = 0; k < 16; k++){
      float4 a = *reinterpret_cast<const float4*>(&As[k][ty * 4]);
      float4 b = *reinterpret_cast<const float4*>(&Bs[k][tx * 4]);
      c[0][0] += a.x * b.x; c[0][1] += a.x * b.y; c[0][2] += a.x * b.z; c[0][3] += a.x * b.w;
      c[1][0] += a.y * b.x; c[1][1] += a.y * b.y; c[1][2] += a.y * b.z; c[1][3] += a.y * b.w;
      c[2][0] += a.z * b.x; c[2][1] += a.z * b.y; c[2][2] += a.z * b.z; c[2][3] += a.z * b.w;
      c[3][0] += a.w * b.x; c[3][1] += a.w * b.y; c[3][2] += a.w * b.z; c[3][3] += a.w * b.w;
    }
    __syncthreads();
  }
  #pragma unroll
  for (int j = 0; j < 4; j++){
    int col = bn + tx * 4 + j;
    float bvv = bias[col];
    #pragma unroll
    for (int i = 0; i < 4; i++){
      int row = bm + ty * 4 + i;
      float v = c[i][j] + bvv;
      if (LAYOUT == 0){
        Cg[(size_t)row * Ng + col] = v;
      } else {
        int b = row / SS, s = row - b * SS;
        int h = col >> 6, d = col & 63;
        Cg[(((size_t)b * NHH + h) * SS + s) * HDD + d] = v;
      }
    }
  }
}

// ---------------- LayerNorm rows of (12544, 512) ----------------
__global__ __launch_bounds__(256) void ln_rows_kernel(const float* __restrict__ y,
    const float* __restrict__ g, const float* __restrict__ bb,
    float* __restrict__ outf)
{
  int r = blockIdx.x, t = threadIdx.x;
  __shared__ float red[256];
  const float* row = y + (size_t)r * EE;
  float v0 = row[t], v1 = row[t + 256];
  red[t] = v0 + v1; __syncthreads();
  for (int st = 128; st > 0; st >>= 1){ if (t < st) red[t] += red[t + st]; __syncthreads(); }
  float mean = red[0] * (1.f / EE); __syncthreads();
  float d0 = v0 - mean, d1 = v1 - mean;
  red[t] = d0 * d0 + d1 * d1; __syncthreads();
  for (int st = 128; st > 0; st >>= 1){ if (t < st) red[t] += red[t + st]; __syncthreads(); }
  float rs = 1.f / sqrtf(red[0] * (1.f / EE) + 1e-5f);
  float* orow = outf + (size_t)r * EE;
  orow[t] = d0 * rs * g[t] + bb[t];
  orow[t + 256] = d1 * rs * g[t + 256] + bb[t + 256];
}

// ---------------- init recurrent state (act[d][b], tr[m][d][b]) ----------------
__global__ __launch_bounds__(256) void init_kernel(const float* __restrict__ sa,
    const float* __restrict__ strace,
    const int* __restrict__ ol, const int* __restrict__ orr,
    float* __restrict__ act, float* __restrict__ tr,
    float* __restrict__ aA, float* __restrict__ bA,
    float* __restrict__ aO, float* __restrict__ bO)
{
  int tid = blockIdx.x * 256 + threadIdx.x;   // 131072
  int b = tid >> 11, d = tid & 2047;
  act[(size_t)d * 64 + b] = sa[d];
  for (int m = 0; m < MM; m++)
    tr[((size_t)(m * DD + d)) * 64 + b] = strace[d * MM + m];
  if (tid < BB * NSS){
    int n = tid & (NSS - 1);
    int b2 = tid >> 9;
    aO[b2 * NSS + n] = sa[ol[n]] * sa[orr[n]];
    bO[b2 * NSS + n] = 1.f; aA[b2 * NSS + n] = 0.f; bA[b2 * NSS + n] = 0.f;
  }
}

// ---------------- fused: sync update + q + qh + attention + Wo  (one block per b) ----------------
__global__ __launch_bounds__(512) void k_front(const float* __restrict__ act,
    float* __restrict__ aA, float* __restrict__ bA,
    const float* __restrict__ decayA,
    const int* __restrict__ il, const int* __restrict__ ir,
    const float* __restrict__ Wq, const float* __restrict__ bq,
    const float* __restrict__ Wqa, const float* __restrict__ bqa,
    const float* __restrict__ kh, const float* __restrict__ vh,
    const float* __restrict__ Wo, const float* __restrict__ bo,
    float* __restrict__ attnproj)
{
  int b = blockIdx.x, t = threadIdx.x;
  __shared__ float sA[NSS];
  __shared__ float q1[EE];
  __shared__ float q2[EE];
  __shared__ float ps[NHH][200];
  __shared__ float ao[EE];

  // phase A: action-sync + q + qh
  {
    int n = t;
    float p = act[(size_t)il[n] * 64 + b] * act[(size_t)ir[n] * 64 + b];
    float r = expf(-fminf(fmaxf(decayA[n], 0.f), 15.f));
    float na = r * aA[b * NSS + n] + p;
    float nb = r * bA[b * NSS + n] + 1.f;
    aA[b * NSS + n] = na; bA[b * NSS + n] = nb;
    sA[n] = na / sqrtf(nb);
    __syncthreads();
    float a0 = 0, a1 = 0, a2 = 0, a3 = 0;
    #pragma unroll 4
    for (int k = 0; k < NSS; k += 4){
      a0 += sA[k]     * Wq[(size_t)(k)     * EE + n];
      a1 += sA[k + 1] * Wq[(size_t)(k + 1) * EE + n];
      a2 += sA[k + 2] * Wq[(size_t)(k + 2) * EE + n];
      a3 += sA[k + 3] * Wq[(size_t)(k + 3) * EE + n];
    }
    q1[n] = bq[n] + ((a0 + a1) + (a2 + a3));
    __syncthreads();
    a0 = a1 = a2 = a3 = 0.f;
    #pragma unroll 4
    for (int k = 0; k < EE; k += 4){
      a0 += q1[k]     * Wqa[(size_t)(k)     * EE + n];
      a1 += q1[k + 1] * Wqa[(size_t)(k + 1) * EE + n];
      a2 += q1[k + 2] * Wqa[(size_t)(k + 2) * EE + n];
      a3 += q1[k + 3] * Wqa[(size_t)(k + 3) * EE + n];
    }
    q2[n] = bqa[n] + ((a0 + a1) + (a2 + a3));
    __syncthreads();
  }

  // phase B: attention; wave = head, lane = score-slot / d
  int h = t >> 6, lane = t & 63;
  const float* khp = kh + ((size_t)(b * NHH + h)) * SS * HDD;
  const float* vhp = vh + ((size_t)(b * NHH + h)) * SS * HDD;
  float4 qreg[16];
  #pragma unroll
  for (int i = 0; i < 16; i++)
    qreg[i] = *reinterpret_cast<const float4*>(&q2[h * 64 + i * 4]);
  float sc[4];
  #pragma unroll
  for (int i = 0; i < 4; i++){
    int s = lane + i * 64;
    float acc = -1e30f;
    if (s < SS){
      const float* kr = khp + (size_t)s * HDD;
      float acc4 = 0.f;
      #pragma unroll
      for (int kk = 0; kk < 16; kk++){
        float4 kv = *reinterpret_cast<const float4*>(kr + kk * 4);
        float4 qv = qreg[kk];
        acc4 += qv.x * kv.x + qv.y * kv.y + qv.z * kv.z + qv.w * kv.w;
      }
      acc = acc4 * 0.125f;
    }
    sc[i] = acc;
  }
  float mx = fmaxf(fmaxf(sc[0], sc[1]), fmaxf(sc[2], sc[3]));
  #pragma unroll
  for (int off = 32; off > 0; off >>= 1)
    mx = fmaxf(mx, __shfl_xor(mx, off, 64));
  float e[4]; float sm = 0.f;
  #pragma unroll
  for (int i = 0; i < 4; i++){
    int s = lane + i * 64;
    e[i] = (s < SS) ? expf(sc[i] - mx) : 0.f;
    sm += e[i];
  }
  #pragma unroll
  for (int off = 32; off > 0; off >>= 1)
    sm += __shfl_xor(sm, off, 64);
  float inv = 1.f / sm;
  #pragma unroll
  for (int i = 0; i < 4; i++){
    int s = lane + i * 64;
    if (s < SS) ps[h][s] = e[i] * inv;
  }
  __syncthreads();
  {
    float p0 = 0, p1 = 0, p2 = 0, p3 = 0;
    for (int s = 0; s < SS; s += 4){
      p0 += ps[h][s]     * vhp[(size_t)(s)     * HDD + lane];
      p1 += ps[h][s + 1] * vhp[(size_t)(s + 1) * HDD + lane];
      p2 += ps[h][s + 2] * vhp[(size_t)(s + 2) * HDD + lane];
      p3 += ps[h][s + 3] * vhp[(size_t)(s + 3) * HDD + lane];
    }
    ao[h * 64 + lane] = (p0 + p1) + (p2 + p3);
  }
  __syncthreads();

  // phase C: attn @ Wo + bo -> attnproj[n][b]
  {
    int n = t;
    float a0 = 0, a1 = 0, a2 = 0, a3 = 0;
    #pragma unroll 4
    for (int k = 0; k < EE; k += 4){
      a0 += ao[k]     * Wo[(size_t)(k)     * EE + n];
      a1 += ao[k + 1] * Wo[(size_t)(k + 1) * EE + n];
      a2 += ao[k + 2] * Wo[(size_t)(k + 2) * EE + n];
      a3 += ao[k + 3] * Wo[(size_t)(k + 3) * EE + n];
    }
    attnproj[(size_t)n * 64 + b] = bo[n] + ((a0 + a1) + (a2 + a3));
  }
}

// ---------------- synapse GEMM with K-split: part[kq](64 x 4096) ----------------
// A = concat(attnproj, act) in [k][b] layout; Wsyn row-major (2560, 4096)
__global__ __launch_bounds__(256) void k_syn(const float* __restrict__ attnproj,
    const float* __restrict__ act, const float* __restrict__ Wsyn,
    float* __restrict__ part)
{
  __shared__ float As[32][68];
  __shared__ float Bs[32][68];
  int t = threadIdx.x;
  int bn = blockIdx.x * 64;
  int kq = blockIdx.y;
  int ty = t >> 4, tx = t & 15;
  int c4 = (t & 15) * 4;
  int kk0 = t >> 4;
  float c[4][4] = {};
  int k0 = kq * KQLEN;
  for (int kt = 0; kt < KQLEN; kt += 32){
    #pragma unroll
    for (int hh = 0; hh < 2; hh++){
      int kk = kk0 + hh * 16;
      int gk = k0 + kt + kk;
      const float* src = (gk < EE) ? (attnproj + (size_t)gk * 64)
                                   : (act + (size_t)(gk - EE) * 64);
      *reinterpret_cast<float4*>(&As[kk][c4]) = *reinterpret_cast<const float4*>(src + c4);
      *reinterpret_cast<float4*>(&Bs[kk][c4]) =
          *reinterpret_cast<const float4*>(Wsyn + (size_t)gk * NSYN + bn + c4);
    }
    __syncthreads();
    #pragma unroll
    for (int k = 0; k < 32; k++){
      float4 a = *reinterpret_cast<const float4*>(&As[k][ty * 4]);
      float4 bv = *reinterpret_cast<const float4*>(&Bs[k][tx * 4]);
      c[0][0] += a.x * bv.x; c[0][1] += a.x * bv.y; c[0][2] += a.x * bv.z; c[0][3] += a.x * bv.w;
      c[1][0] += a.y * bv.x; c[1][1] += a.y * bv.y; c[1][2] += a.y * bv.z; c[1][3] += a.y * bv.w;
      c[2][0] += a.z * bv.x; c[2][1] += a.z * bv.y; c[2][2] += a.z * bv.z; c[2][3] += a.z * bv.w;
      c[3][0] += a.w * bv.x; c[3][1] += a.w * bv.y; c[3][2] += a.w * bv.z; c[3][3] += a.w * bv.w;
    }
    __syncthreads();
  }
  #pragma unroll
  for (int i = 0; i < 4; i++){
    int row = ty * 4 + i;
    float* dst = part + ((size_t)kq * 64 + row) * NSYN + bn + tx * 4;
    dst[0] = c[i][0]; dst[1] = c[i][1]; dst[2] = c[i][2]; dst[3] = c[i][3];
  }
}

// ---------------- sum partials + bias + GLU + LayerNorm -> trace slot ----------------
__global__ __launch_bounds__(256) void k_gluln(const float* __restrict__ part,
    const float* __restrict__ bsyn,
    const float* __restrict__ g, const float* __restrict__ bb,
    float* __restrict__ tr, int slot)
{
  int b = blockIdx.x, t = threadIdx.x;
  __shared__ float u[DD];
  __shared__ float red[256];
  float ls = 0.f;
  for (int i = t; i < DD; i += 256){
    float x0 = bsyn[i], x1 = bsyn[DD + i];
    #pragma unroll
    for (int kq = 0; kq < KQ; kq++){
      const float* pr = part + ((size_t)kq * 64 + b) * NSYN;
      x0 += pr[i]; x1 += pr[DD + i];
    }
    float uu = x0 * sigm(x1);
    u[i] = uu; ls += uu;
  }
  red[t] = ls; __syncthreads();
  for (int st = 128; st > 0; st >>= 1){ if (t < st) red[t] += red[t + st]; __syncthreads(); }
  float mean = red[0] * (1.f / DD); __syncthreads();
  float lq = 0.f;
  for (int i = t; i < DD; i += 256){ float dv = u[i] - mean; lq += dv * dv; }
  red[t] = lq; __syncthreads();
  for (int st = 128; st > 0; st >>= 1){ if (t < st) red[t] += red[t + st]; __syncthreads(); }
  float rs = 1.f / sqrtf(red[0] * (1.f / DD) + 1e-5f);
  for (int i = t; i < DD; i += 256)
    tr[((size_t)(slot * DD + i)) * 64 + b] = (u[i] - mean) * rs * g[i] + bb[i];
}

// ---------------- per-neuron MLP: wave = 64 batch lanes for one d ----------------
__global__ __launch_bounds__(256) void k_nlm(const float* __restrict__ tr,
    const float* __restrict__ w1, const float* __restrict__ b1,
    const float* __restrict__ w2, const float* __restrict__ b2,
    float* __restrict__ act, int ts)
{
  __shared__ float w1s[4][1600];
  __shared__ float w2s[4][64];
  __shared__ float b1s[4][64];
  int t = threadIdx.x;
  int d0 = blockIdx.x * 4;
  for (int jh = t; jh < 1600; jh += 256){
    float4 v = *reinterpret_cast<const float4*>(w1 + (size_t)jh * DD + d0);
    w1s[0][jh] = v.x; w1s[1][jh] = v.y; w1s[2][jh] = v.z; w1s[3][jh] = v.w;
  }
  if (t < 64){
    float4 v = *reinterpret_cast<const float4*>(w2 + (size_t)t * DD + d0);
    w2s[0][t] = v.x; w2s[1][t] = v.y; w2s[2][t] = v.z; w2s[3][t] = v.w;
  }
  {
    int dd = t >> 6, hh = t & 63;
    b1s[dd][hh] = b1[(size_t)(d0 + dd) * 64 + hh];
  }
  __syncthreads();
  int lane = t & 63, dd = t >> 6;
  int d = d0 + dd;
  float hp[64];
  #pragma unroll
  for (int h2 = 0; h2 < 64; h2++) hp[h2] = b1s[dd][h2];
  for (int j = 0; j < MM; j++){
    int slot = (ts + 1 + j) % MM;
    float tv = tr[((size_t)(slot * DD + d)) * 64 + lane];
    const float4* wrow = reinterpret_cast<const float4*>(&w1s[dd][j * 64]);
    #pragma unroll
    for (int h4 = 0; h4 < 16; h4++){
      float4 wv = wrow[h4];
      hp[h4 * 4 + 0] += tv * wv.x;
      hp[h4 * 4 + 1] += tv * wv.y;
      hp[h4 * 4 + 2] += tv * wv.z;
      hp[h4 * 4 + 3] += tv * wv.w;
    }
  }
  float o0 = b2[d * 2], o1 = b2[d * 2 + 1];
  #pragma unroll
  for (int h2 = 0; h2 < HNN; h2++){
    float hh2 = hp[h2] * sigm(hp[h2 + HNN]);
    o0 += hh2 * w2s[dd][h2 * 2];
    o1 += hh2 * w2s[dd][h2 * 2 + 1];
  }
  act[(size_t)d * 64 + lane] = o0 * sigm(o1);
}

// ---------------- out-sync + prediction + certainty ----------------
__global__ __launch_bounds__(512) void k_out(const float* __restrict__ act,
    float* __restrict__ aO, float* __restrict__ bO,
    const float* __restrict__ decayO,
    const int* __restrict__ ol, const int* __restrict__ orr,
    const float* __restrict__ Wout, const float* __restrict__ bout,
    float* __restrict__ dout, int ts)
{
  int b = blockIdx.x, n = threadIdx.x;
  __shared__ float so[NSS];
  __shared__ float pl[OUTN];
  __shared__ float red[512];
  float p = act[(size_t)ol[n] * 64 + b] * act[(size_t)orr[n] * 64 + b];
  float r = expf(-fminf(fmaxf(decayO[n], 0.f), 15.f));
  float na = r * aO[b * NSS + n] + p;
  float nb = r * bO[b * NSS + n] + 1.f;
  aO[b * NSS + n] = na; bO[b * NSS + n] = nb;
  float sv = na / sqrtf(nb);
  so[n] = sv;
  if (ts == TT - 1) dout[SYNC_OFF + b * NSS + n] = sv;
  __syncthreads();
  {
    int n2 = n + 512;
    bool v2 = (n2 < OUTN);
    int n2s = v2 ? n2 : n;
    float a0 = 0, a1 = 0, a2 = 0, a3 = 0, c0 = 0, c1 = 0, c2 = 0, c3 = 0;
    #pragma unroll 4
    for (int k = 0; k < NSS; k += 4){
      float s0 = so[k], s1 = so[k + 1], s2 = so[k + 2], s3 = so[k + 3];
      a0 += s0 * Wout[(size_t)(k)     * OUTN + n];
      a1 += s1 * Wout[(size_t)(k + 1) * OUTN + n];
      a2 += s2 * Wout[(size_t)(k + 2) * OUTN + n];
      a3 += s3 * Wout[(size_t)(k + 3) * OUTN + n];
      c0 += s0 * Wout[(size_t)(k)     * OUTN + n2s];
      c1 += s1 * Wout[(size_t)(k + 1) * OUTN + n2s];
      c2 += s2 * Wout[(size_t)(k + 2) * OUTN + n2s];
      c3 += s3 * Wout[(size_t)(k + 3) * OUTN + n2s];
    }
    float p1v = bout[n] + ((a0 + a1) + (a2 + a3));
    pl[n] = p1v;
    dout[((size_t)b * OUTN + n) * TT + ts] = p1v;
    if (v2){
      float p2v = bout[n2] + ((c0 + c1) + (c2 + c3));
      pl[n2] = p2v;
      dout[((size_t)b * OUTN + n2) * TT + ts] = p2v;
    }
  }
  __syncthreads();
  float mx = pl[n];
  if (n + 512 < OUTN) mx = fmaxf(mx, pl[n + 512]);
  red[n] = mx; __syncthreads();
  for (int st = 256; st > 0; st >>= 1){ if (n < st) red[n] = fmaxf(red[n], red[n + st]); __syncthreads(); }
  mx = red[0]; __syncthreads();
  float z = 0.f, s1e = 0.f;
  {
    float e0 = expf(pl[n] - mx);
    z += e0; s1e += e0 * (pl[n] - mx);
    if (n + 512 < OUTN){
      float e1 = expf(pl[n + 512] - mx);
      z += e1; s1e += e1 * (pl[n + 512] - mx);
    }
  }
  red[n] = z; __syncthreads();
  for (int st = 256; st > 0; st >>= 1){ if (n < st) red[n] += red[n + st]; __syncthreads(); }
  z = red[0]; __syncthreads();
  red[n] = s1e; __syncthreads();
  for (int st = 256; st > 0; st >>= 1){ if (n < st) red[n] += red[n + st]; __syncthreads(); }
  s1e = red[0];
  if (n == 0){
    float logZ = logf(z);
    float ne = (logZ - s1e / z) * (1.f / logf(1000.f));
    dout[CERT_OFF + (b * 2 + 0) * TT + ts] = ne;
    dout[CERT_OFF + (b * 2 + 1) * TT + ts] = 1.f - ne;
  }
}

extern "C" void kernel_launch(void* const* d_in, const int* in_sizes, int n_in,
                              void* d_out, int out_size, void* d_ws, size_t ws_size,
                              hipStream_t stream)
{
  const float* x    = (const float*)d_in[0];
  const float* Wkv  = (const float*)d_in[1];
  const float* bkv  = (const float*)d_in[2];
  const float* gkv  = (const float*)d_in[3];
  const float* bkv2 = (const float*)d_in[4];
  const float* Wq   = (const float*)d_in[5];
  const float* bq   = (const float*)d_in[6];
  const float* Wqa  = (const float*)d_in[7];
  const float* bqa  = (const float*)d_in[8];
  const float* Wka  = (const float*)d_in[9];
  const float* bka  = (const float*)d_in[10];
  const float* Wva  = (const float*)d_in[11];
  const float* bva  = (const float*)d_in[12];
  const float* Wo   = (const float*)d_in[13];
  const float* bo   = (const float*)d_in[14];
  const float* Wsyn = (const float*)d_in[15];
  const float* bsyn = (const float*)d_in[16];
  const float* gsyn = (const float*)d_in[17];
  const float* bsn  = (const float*)d_in[18];
  const float* w1   = (const float*)d_in[19];
  const float* b1   = (const float*)d_in[20];
  const float* w2   = (const float*)d_in[21];
  const float* b2   = (const float*)d_in[22];
  const float* sact = (const float*)d_in[23];
  const float* strc = (const float*)d_in[24];
  const float* dcA  = (const float*)d_in[25];
  const float* dcO  = (const float*)d_in[26];
  const float* Wout = (const float*)d_in[27];
  const float* bout = (const float*)d_in[28];
  const int* ial = (const int*)d_in[29];
  const int* iar = (const int*)d_in[30];
  const int* iol = (const int*)d_in[31];
  const int* ior = (const int*)d_in[32];

  char* ws = (char*)d_ws;
  float* kh = (float*)ws;                         // 25,690,112 B
  float* vh = (float*)(ws + 25690112);            // 25,690,112 B
  char* scr = ws + 51380224;
  float* kvnf  = (float*)ws;                      // pre-LN (aliases kh; dead before kh written)
  float* kvnln = (float*)scr;                     // post-LN (dead before init)
  float* tr       = (float*)scr;                  // 13,107,200 B  [m][d][b]
  float* act      = (float*)(scr + 13107200);     // 524,288      [d][b]
  float* aA       = (float*)(scr + 13631488);
  float* bA       = (float*)(scr + 13762560);
  float* aO       = (float*)(scr + 13893632);
  float* bO       = (float*)(scr + 14024704);
  float* attnproj = (float*)(scr + 14155776);     // [n][b]
  float* part     = (float*)(scr + 14286848);     // 8,388,608 B (8 x 64 x 4096 f32)
  float* dout = (float*)d_out;

  // precompute: kv = LN(x@Wkv+bkv); kh = kv@Wka+bka; vh = kv@Wva+bva
  sgemm<0><<<dim3(196, 8), 256, 0, stream>>>(x, Wkv, bkv, kvnf, 12544, EE, EE);
  ln_rows_kernel<<<12544, 256, 0, stream>>>(kvnf, gkv, bkv2, kvnln);
  sgemm<1><<<dim3(196, 8), 256, 0, stream>>>(kvnln, Wka, bka, kh, 12544, EE, EE);
  sgemm<1><<<dim3(196, 8), 256, 0, stream>>>(kvnln, Wva, bva, vh, 12544, EE, EE);
  init_kernel<<<512, 256, 0, stream>>>(sact, strc, iol, ior, act, tr, aA, bA, aO, bO);

  for (int t = 0; t < TT; t++){
    k_front<<<64, 512, 0, stream>>>(act, aA, bA, dcA, ial, iar, Wq, bq, Wqa, bqa,
                                    kh, vh, Wo, bo, attnproj);
    k_syn<<<dim3(64, KQ), 256, 0, stream>>>(attnproj, act, Wsyn, part);
    k_gluln<<<64, 256, 0, stream>>>(part, bsyn, gsyn, bsn, tr, t % MM);
    k_nlm<<<512, 256, 0, stream>>>(tr, w1, b1, w2, b2, act, t);
    k_out<<<64, 512, 0, stream>>>(act, aO, bO, dcO, iol, ior, Wout, bout, dout, t);
  }
}